// Round 12
// baseline (76.748 us; speedup 1.0000x reference)
//
#include <hip/hip_runtime.h>
#include <math.h>

// ChamferDistance: B=4, N=M=8192, 3-D fp32 points.
// out[0] = mean_i sqrt(min_j d2)*w  +  mean_j sqrt(min_i d2)
//
// MFMA formulation (R6+): d2 = qsq + (rsq - 2 q.r) as a K=5 dot on
// v_mfma_f32_32x32x16_f16 (32 refs x 32 queries = 1024 pairs/inst):
//   A (refs)    = (-2rx,-2ry,-2rz, rsq_hi, rsq_lo, 0,0,0) f16, lanes 0-31
//   B (queries) = (  qx,  qy,  qz,   1,      1,    0,0,0) f16, lanes 0-31
// lanes 32-63 (k=8..15) zero. D: col=lane&31=query; 16 regs x lane-half =
// 32 refs -> per-lane min3 fold + one shfl_xor(32). absmax 0.0 verified.
//
// R12: AGPR-copy hypothesis test. R7-R11 are invariant (~76us) to ILP,
// dispatch count, and residency; nn measures ~30us vs an ~8us pipe model.
// Common factor: 2-4 live f32x16 D-tiles at 80-110 VGPR demand vs 85-128
// caps -> allocator likely parks D in AGPRs -> v_accvgpr_read per fold
// operand (~3x VALU bloat), which FITS the 30us and the invariance.
// Change exactly one thing vs R10: ONE query tile per wave (QPW=32).
// Live regs ~45 << 64 cap of __launch_bounds__(256,8) -> all-VGPR
// guaranteed, zero copies possible. Downside bound: DS doubles (1
// ds_read_b128 per MFMA, ~10us total) if the theory is wrong.

#define EPS 1e-8f

typedef _Float16 f16x8 __attribute__((ext_vector_type(8)));
typedef float    f32x16 __attribute__((ext_vector_type(16)));

constexpr int B_    = 4;
constexpr int N_    = 8192;          // points per batch (N == M)
constexpr int TPB   = 256;           // 4 waves
constexpr int QPW   = 32;            // queries per wave (ONE tile of 32)
constexpr int QPB   = 4 * QPW;       // 128 queries per block
constexpr int RCH   = 8;             // ref chunks (grid.y)
constexpr int CHUNK = N_ / RCH;      // 1024 refs staged per block (16 KB)
constexpr int RB    = 64;            // reduce blocks

// grid: (N/QPB=64, RCH=8, 2*B=8) = 4096 blocks; 8 resident blocks/CU
// (LDS 16.5K x 8 = 132K <= 160K), 8 waves/SIMD.
// part layout: part[(zb*RCH + c)*N + q]  (zb = dir*4+b), 2 MB total.
__global__ __launch_bounds__(TPB, 8)
void nn_mfma_kernel(const float* __restrict__ src, const float* __restrict__ tgt,
                    float* __restrict__ part, float* __restrict__ out)
{
    __shared__ f16x8 sref[CHUNK + 64];   // +64: zero slot & safe prefetch pad

    if (blockIdx.x == 0 && blockIdx.y == 0 && blockIdx.z == 0 && threadIdx.x == 0)
        out[0] = 0.f;                    // reduce (next dispatch) atomicAdds

    const int zb  = blockIdx.z;
    const int dir = zb >> 2;            // 0: src queries tgt, 1: tgt queries src
    const int b   = zb & 3;
    const float* Rraw = (dir ? src : tgt) + ((size_t)b * N_ + (size_t)blockIdx.y * CHUNK) * 3;
    const float* Qraw = (dir ? tgt : src) + (size_t)b * N_ * 3;
    float* opart = part + ((size_t)zb * RCH + blockIdx.y) * N_;

    const int tid = threadIdx.x;
    const _Float16 h0 = (_Float16)0.f;
    const _Float16 h1 = (_Float16)1.f;

    // stage + quantize refs inline: (-2x,-2y,-2z, rsq_hi, rsq_lo, 0,0,0)
    for (int k = tid; k < CHUNK; k += TPB) {
        const float* rp = Rraw + (size_t)k * 3;
        _Float16 hx = (_Float16)rp[0], hy = (_Float16)rp[1], hz = (_Float16)rp[2];
        float fx = (float)hx, fy = (float)hy, fz = (float)hz;
        float rsq = fx * fx + fy * fy + fz * fz;
        _Float16 rh = (_Float16)rsq;
        _Float16 rl = (_Float16)(rsq - (float)rh);
        f16x8 a = {(_Float16)(-2.f * fx), (_Float16)(-2.f * fy),
                   (_Float16)(-2.f * fz), rh, rl, h0, h0, h0};
        sref[k] = a;
    }
    if (tid < 64) {
        f16x8 z = {h0, h0, h0, h0, h0, h0, h0, h0};
        sref[CHUNK + tid] = z;
    }

    const int lane = tid & 63;
    const int wv   = tid >> 6;
    const int l31  = lane & 31;
    const int half = lane >> 5;          // 0: carries data (k=0..7), 1: zeros
    const int qb   = blockIdx.x * QPB + wv * QPW;

    // ONE B fragment quantized inline; lanes 32-63 stay zero (k=8..15)
    f16x8 B0 = {h0, h0, h0, h0, h0, h0, h0, h0};
    float qs0 = 0.f;
    if (half == 0) {
        const float* q0 = Qraw + (size_t)(qb + l31) * 3;
        _Float16 ax = (_Float16)q0[0], ay = (_Float16)q0[1], az = (_Float16)q0[2];
        float fax = (float)ax, fay = (float)ay, faz = (float)az;
        B0 = f16x8{ax, ay, az, h1, h1, h0, h0, h0};
        qs0 = fax * fax + fay * fay + faz * faz;
    }
    __syncthreads();

    const f32x16 zc = {};   // expected to fold to inline 0 for MFMA src2

    // K-loop: 1 ds_read_b128 + 1 MFMA + 8 min3 per iter; single D-tile live.
    int idx = (half == 0) ? l31 : CHUNK;
    const int step = (half == 0) ? 32 : 0;
    float mn0a = 3.0e38f, mn0b = 3.0e38f;

    f16x8 a = sref[idx];
    idx += step;
    for (int s = 0; s < CHUNK / 32; ++s) {
        f16x8 an = sref[idx];            // tail prefetch lands in pad (unused)
        idx += step;
        f32x16 d0 = __builtin_amdgcn_mfma_f32_32x32x16_f16(a, B0, zc, 0, 0, 0);
#pragma unroll
        for (int r = 0; r < 8; r += 2)
            mn0a = fminf(fminf(d0[r], d0[r + 1]), mn0a);   // v_min3_f32
#pragma unroll
        for (int r = 8; r < 16; r += 2)
            mn0b = fminf(fminf(d0[r], d0[r + 1]), mn0b);
        a = an;
    }

    float mn0 = fminf(mn0a, mn0b);
    // rows split across lane halves: one xor-32 merge covers all 32 refs/tile
    mn0 = fminf(mn0, __shfl_xor(mn0, 32));
    if (half == 0)
        opart[qb + l31] = fmaxf(mn0 + qs0, 0.f);   // plain store, no init

}

// reduce: per query min over RCH partials -> sqrt -> weight -> sum ->
// atomicAdd into out[0] (zeroed by nn). 2 MB of partials, L2-resident.
__global__ __launch_bounds__(TPB)
void reduce_kernel(const float* __restrict__ part,
                   const float* __restrict__ w,
                   float* __restrict__ out)
{
    const int Q = 2 * B_ * N_;               // 65536 queries
    const float invBN = 1.0f / (float)(B_ * N_);

    float sum = 0.0f;
    for (int t = blockIdx.x * TPB + threadIdx.x; t < Q; t += RB * TPB) {
        const int zb = t >> 13;              // t / N_
        const int qn = t & (N_ - 1);
        const float* p = part + ((size_t)zb * RCH) * N_ + qn;
        float m = p[0];
#pragma unroll
        for (int c = 1; c < RCH; ++c) m = fminf(m, p[(size_t)c * N_]);
        float d = sqrtf(m + EPS);
        sum += (zb < 4) ? d * w[(size_t)zb * N_ + qn] : d;
    }
    sum *= invBN;

    __shared__ float ss[TPB / 64];
    int lane = threadIdx.x & 63;
    int wid  = threadIdx.x >> 6;
#pragma unroll
    for (int off = 32; off > 0; off >>= 1) sum += __shfl_down(sum, off);
    if (lane == 0) ss[wid] = sum;
    __syncthreads();
    if (threadIdx.x == 0) {
        float s = 0.0f;
#pragma unroll
        for (int i = 0; i < TPB / 64; ++i) s += ss[i];
        atomicAdd(out, s);
    }
}

extern "C" void kernel_launch(void* const* d_in, const int* in_sizes, int n_in,
                              void* d_out, int out_size, void* d_ws, size_t ws_size,
                              hipStream_t stream)
{
    const float* src = (const float*)d_in[0];   // (B, N, 3)
    const float* tgt = (const float*)d_in[1];   // (B, M, 3)
    const float* w   = (const float*)d_in[2];   // (B, N)
    float* out = (float*)d_out;

    float* part = (float*)d_ws;   // [2*B][RCH][N] = 2 MB, fully overwritten

    dim3 grid(N_ / QPB, RCH, 2 * B_);   // 64 x 8 x 8 = 4096 blocks
    nn_mfma_kernel<<<grid, TPB, 0, stream>>>(src, tgt, part, out);

    reduce_kernel<<<RB, TPB, 0, stream>>>(part, w, out);
}

// Round 13
// 75.886 us; speedup vs baseline: 1.0114x; 1.0114x over previous
//
#include <hip/hip_runtime.h>
#include <math.h>

// ChamferDistance: B=4, N=M=8192, 3-D fp32 points.
// out[0] = mean_i sqrt(min_j d2)*w  +  mean_j sqrt(min_i d2)
//
// MFMA formulation (R6+): d2 = qsq + (rsq - 2 q.r) as a K=5 dot on
// v_mfma_f32_32x32x16_f16 (32 refs x 32 queries = 1024 pairs/inst):
//   A (refs)    = (-2rx,-2ry,-2rz, rsq_hi, rsq_lo, 0,0,0) f16, lanes 0-31
//   B (queries) = (  qx,  qy,  qz,   1,      1,    0,0,0) f16, lanes 0-31
// lanes 32-63 (k=8..15) zero. D: col=lane&31=query; 16 regs x lane-half =
// 32 refs -> per-lane min3 fold + one shfl_xor(32). absmax 0.0 verified.
//
// R13: cross-iteration D pipelining. Falsified so far: ILP count (R9),
// dispatch overhead (R10), residency (R11), AGPR copies (R12) — nn is
// ~22us vs 6.9us matrix floor, invariant to all. Remaining common factor:
// every variant folds D immediately after its producing MFMA -> per-iter
// stall on MFMA result latency + dest-read hazard, wave-local, occupancy-
// invariant if hazard-padded at issue. Fix: explicit depth-1 ping-pong
// (unrolled x2, no copies) — fold fragment k-1's D while fragment k's
// MFMAs are in flight (~70+ cyc separation). ~108 live regs -> lb(256,4).

#define EPS 1e-8f

typedef _Float16 f16x8 __attribute__((ext_vector_type(8)));
typedef float    f32x16 __attribute__((ext_vector_type(16)));

constexpr int B_    = 4;
constexpr int N_    = 8192;          // points per batch (N == M)
constexpr int TPB   = 256;           // 4 waves
constexpr int QPW   = 64;            // queries per wave (2 tiles of 32)
constexpr int QPB   = 4 * QPW;       // 256 queries per block
constexpr int RCH   = 8;             // ref chunks (grid.y)
constexpr int CHUNK = N_ / RCH;      // 1024 refs staged per block (16 KB)
constexpr int RB    = 64;            // reduce blocks

#define FOLD(d, ma, mb)                                         \
    _Pragma("unroll")                                           \
    for (int r = 0; r < 8; r += 2)                              \
        ma = fminf(fminf(d[r], d[r + 1]), ma);                  \
    _Pragma("unroll")                                           \
    for (int r = 8; r < 16; r += 2)                             \
        mb = fminf(fminf(d[r], d[r + 1]), mb);

// grid: (N/QPB=32, RCH=8, 2*B=8) = 2048 blocks.
// part layout: part[(zb*RCH + c)*N + q]  (zb = dir*4+b), 2 MB total.
__global__ __launch_bounds__(TPB, 4)
void nn_mfma_kernel(const float* __restrict__ src, const float* __restrict__ tgt,
                    float* __restrict__ part, float* __restrict__ out)
{
    __shared__ f16x8 sref[CHUNK + 64];   // +64: zero slots (also absorb tail reads)

    if (blockIdx.x == 0 && blockIdx.y == 0 && blockIdx.z == 0 && threadIdx.x == 0)
        out[0] = 0.f;                    // reduce (next dispatch) atomicAdds

    const int zb  = blockIdx.z;
    const int dir = zb >> 2;            // 0: src queries tgt, 1: tgt queries src
    const int b   = zb & 3;
    const float* Rraw = (dir ? src : tgt) + ((size_t)b * N_ + (size_t)blockIdx.y * CHUNK) * 3;
    const float* Qraw = (dir ? tgt : src) + (size_t)b * N_ * 3;
    float* opart = part + ((size_t)zb * RCH + blockIdx.y) * N_;

    const int tid = threadIdx.x;
    const _Float16 h0 = (_Float16)0.f;
    const _Float16 h1 = (_Float16)1.f;

    // stage + quantize refs inline: (-2x,-2y,-2z, rsq_hi, rsq_lo, 0,0,0)
    for (int k = tid; k < CHUNK; k += TPB) {
        const float* rp = Rraw + (size_t)k * 3;
        _Float16 hx = (_Float16)rp[0], hy = (_Float16)rp[1], hz = (_Float16)rp[2];
        float fx = (float)hx, fy = (float)hy, fz = (float)hz;
        float rsq = fx * fx + fy * fy + fz * fz;
        _Float16 rh = (_Float16)rsq;
        _Float16 rl = (_Float16)(rsq - (float)rh);
        f16x8 a = {(_Float16)(-2.f * fx), (_Float16)(-2.f * fy),
                   (_Float16)(-2.f * fz), rh, rl, h0, h0, h0};
        sref[k] = a;
    }
    if (tid < 64) {
        f16x8 z = {h0, h0, h0, h0, h0, h0, h0, h0};
        sref[CHUNK + tid] = z;
    }

    const int lane = tid & 63;
    const int wv   = tid >> 6;
    const int l31  = lane & 31;
    const int half = lane >> 5;          // 0: carries data (k=0..7), 1: zeros
    const int qb   = blockIdx.x * QPB + wv * QPW;

    // B fragments quantized inline; lanes 32-63 stay zero (k=8..15)
    f16x8 B0 = {h0, h0, h0, h0, h0, h0, h0, h0};
    f16x8 B1 = B0;
    float qs0 = 0.f, qs1 = 0.f;
    if (half == 0) {
        const float* q0 = Qraw + (size_t)(qb + l31) * 3;
        const float* q1 = Qraw + (size_t)(qb + 32 + l31) * 3;
        _Float16 ax = (_Float16)q0[0], ay = (_Float16)q0[1], az = (_Float16)q0[2];
        _Float16 bx = (_Float16)q1[0], by = (_Float16)q1[1], bz = (_Float16)q1[2];
        float fax = (float)ax, fay = (float)ay, faz = (float)az;
        float fbx = (float)bx, fby = (float)by, fbz = (float)bz;
        B0 = f16x8{ax, ay, az, h1, h1, h0, h0, h0};
        B1 = f16x8{bx, by, bz, h1, h1, h0, h0, h0};
        qs0 = fax * fax + fay * fay + faz * faz;
        qs1 = fbx * fbx + fby * fby + fbz * fbz;
    }
    __syncthreads();

    const f32x16 zc = {};

    // Depth-1 pipelined K-loop over 32 A-fragments, unrolled x2 (ping-pong,
    // no register copies): fold fragment k-1's D while fragment k's MFMAs
    // are in flight. Frag trace: pre: dA=f0, a=f1. iter s: dB=f(2s+1),
    // fold dA=f(2s), dA=f(2s+2), fold dB=f(2s+1). post: dB=f31, fold both.
    int idx = (half == 0) ? l31 : CHUNK;
    const int step = (half == 0) ? 32 : 0;
    float mn0a = 3.0e38f, mn0b = 3.0e38f, mn1a = 3.0e38f, mn1b = 3.0e38f;

    f16x8 a = sref[idx];
    idx += step;
    f32x16 dA0 = __builtin_amdgcn_mfma_f32_32x32x16_f16(a, B0, zc, 0, 0, 0);
    f32x16 dA1 = __builtin_amdgcn_mfma_f32_32x32x16_f16(a, B1, zc, 0, 0, 0);
    a = sref[idx];
    idx += step;
    for (int s = 0; s < 15; ++s) {
        f32x16 dB0 = __builtin_amdgcn_mfma_f32_32x32x16_f16(a, B0, zc, 0, 0, 0);
        f32x16 dB1 = __builtin_amdgcn_mfma_f32_32x32x16_f16(a, B1, zc, 0, 0, 0);
        a = sref[idx];
        idx += step;
        FOLD(dA0, mn0a, mn0b)
        FOLD(dA1, mn1a, mn1b)
        dA0 = __builtin_amdgcn_mfma_f32_32x32x16_f16(a, B0, zc, 0, 0, 0);
        dA1 = __builtin_amdgcn_mfma_f32_32x32x16_f16(a, B1, zc, 0, 0, 0);
        a = sref[idx];
        idx += step;
        FOLD(dB0, mn0a, mn0b)
        FOLD(dB1, mn1a, mn1b)
    }
    {
        f32x16 dB0 = __builtin_amdgcn_mfma_f32_32x32x16_f16(a, B0, zc, 0, 0, 0);
        f32x16 dB1 = __builtin_amdgcn_mfma_f32_32x32x16_f16(a, B1, zc, 0, 0, 0);
        FOLD(dA0, mn0a, mn0b)
        FOLD(dA1, mn1a, mn1b)
        FOLD(dB0, mn0a, mn0b)
        FOLD(dB1, mn1a, mn1b)
    }

    float mn0 = fminf(mn0a, mn0b);
    float mn1 = fminf(mn1a, mn1b);
    // rows split across lane halves: one xor-32 merge covers all 32 refs/tile
    mn0 = fminf(mn0, __shfl_xor(mn0, 32));
    mn1 = fminf(mn1, __shfl_xor(mn1, 32));
    if (half == 0) {
        opart[qb + l31]      = fmaxf(mn0 + qs0, 0.f);   // plain store, no init
        opart[qb + 32 + l31] = fmaxf(mn1 + qs1, 0.f);
    }
}

// reduce: per query min over RCH partials -> sqrt -> weight -> sum ->
// atomicAdd into out[0] (zeroed by nn). 2 MB of partials, L2-resident.
__global__ __launch_bounds__(TPB)
void reduce_kernel(const float* __restrict__ part,
                   const float* __restrict__ w,
                   float* __restrict__ out)
{
    const int Q = 2 * B_ * N_;               // 65536 queries
    const float invBN = 1.0f / (float)(B_ * N_);

    float sum = 0.0f;
    for (int t = blockIdx.x * TPB + threadIdx.x; t < Q; t += RB * TPB) {
        const int zb = t >> 13;              // t / N_
        const int qn = t & (N_ - 1);
        const float* p = part + ((size_t)zb * RCH) * N_ + qn;
        float m = p[0];
#pragma unroll
        for (int c = 1; c < RCH; ++c) m = fminf(m, p[(size_t)c * N_]);
        float d = sqrtf(m + EPS);
        sum += (zb < 4) ? d * w[(size_t)zb * N_ + qn] : d;
    }
    sum *= invBN;

    __shared__ float ss[TPB / 64];
    int lane = threadIdx.x & 63;
    int wid  = threadIdx.x >> 6;
#pragma unroll
    for (int off = 32; off > 0; off >>= 1) sum += __shfl_down(sum, off);
    if (lane == 0) ss[wid] = sum;
    __syncthreads();
    if (threadIdx.x == 0) {
        float s = 0.0f;
#pragma unroll
        for (int i = 0; i < TPB / 64; ++i) s += ss[i];
        atomicAdd(out, s);
    }
}

extern "C" void kernel_launch(void* const* d_in, const int* in_sizes, int n_in,
                              void* d_out, int out_size, void* d_ws, size_t ws_size,
                              hipStream_t stream)
{
    const float* src = (const float*)d_in[0];   // (B, N, 3)
    const float* tgt = (const float*)d_in[1];   // (B, M, 3)
    const float* w   = (const float*)d_in[2];   // (B, N)
    float* out = (float*)d_out;

    float* part = (float*)d_ws;   // [2*B][RCH][N] = 2 MB, fully overwritten

    dim3 grid(N_ / QPB, RCH, 2 * B_);   // 32 x 8 x 8 = 2048 blocks
    nn_mfma_kernel<<<grid, TPB, 0, stream>>>(src, tgt, part, out);

    reduce_kernel<<<RB, TPB, 0, stream>>>(part, w, out);
}